// Round 5
// baseline (337.117 us; speedup 1.0000x reference)
//
#include <hip/hip_runtime.h>
#include <hip/hip_bf16.h>
#include <math.h>

// B=32, H=64, W=64, C_IN=384, C_HID=128
// conv3x3(pad1)+b1 -> relu -> conv1x1+b2 -> sigmoid, NHWC fp32.
// Implicit GEMM, halo-LDS (double-buffered), tap-sharing.
// R5 = R4 + NO-DRAIN BARRIERS (the T3/T4 lever):
//   * In-loop __syncthreads() replaced by {s_waitcnt lgkmcnt(0); s_barrier;
//     sched_barrier(0)}. __syncthreads emits vmcnt(0) which was DRAINING
//     the in-flight B/staging prefetches at all 12 chunk barriers (R4's
//     pipeline was structurally cancelled). The loop has no global-write
//     hazards: only x/W1b reads in flight; LDS ordering needs lgkmcnt only.
//     Each wave drains its own ds_writes/reads pre-barrier -> double-buffer
//     RAW/WAR sound.
//   * Keep R4: 8x16 tile (M=128), 256 thr (4 waves x N=32), acc[8][2]=64
//     AGPR, B ping-pong (bfU/bfV) 1 phase ahead, 2-chunk-unrolled c-loop,
//     s_setprio around MFMA, flat [px][32ch] halo, no swizzle.
//   * Rationale: R2 hit 959 TF-equiv = the known ~900-960 TF ceiling of
//     the 2-barrier drain structure; occupancy/LDS/B-depth levers all
//     proven null inside it (R1-R4). Counted/no-drain vmem is the
//     documented exit (m201/m218: counted-vs-drain0 = +38-73% on GEMM).

typedef __attribute__((ext_vector_type(8))) unsigned short ushort8;
typedef __attribute__((ext_vector_type(8))) __bf16 bf16x8;
typedef __attribute__((ext_vector_type(4))) float floatx4;

#define HPX2 180           // 10*18 halo pixels
#define E 5760             // HPX2*32 elems per chunk buffer

// No-drain barrier: LDS-only drain, vmem stays in flight across it.
#define BARRIER_NODRAIN()                                 \
  asm volatile("s_waitcnt lgkmcnt(0)" ::: "memory");      \
  __builtin_amdgcn_s_barrier();                           \
  __builtin_amdgcn_sched_barrier(0);

static __device__ __forceinline__ unsigned short f2bf_rne(float f) {
  union { float f; unsigned int u; } x; x.f = f;
  unsigned int u = x.u;
  return (unsigned short)((u + 0x7fffu + ((u >> 16) & 1u)) >> 16);
}

static __device__ __forceinline__ ushort8 pack8(const float* v) {
  ushort8 r;
#pragma unroll
  for (int i = 0; i < 4; ++i) {
    __hip_bfloat162 p = __float22bfloat162_rn(make_float2(v[2 * i], v[2 * i + 1]));
    union { __hip_bfloat162 b; unsigned int u; } c;
    c.b = p;
    r[2 * i] = (unsigned short)(c.u & 0xffffu);
    r[2 * i + 1] = (unsigned short)(c.u >> 16);
  }
  return r;
}

// W1 (3,3,384,128 HWIO fp32) -> bf16 W1b[kk][n][c], kk=o*12+chunk, n=0..127, c=0..31.
__global__ void prep_w1_kernel(const float* __restrict__ W1,
                               unsigned short* __restrict__ W1b) {
  __shared__ unsigned short tile[32 * 128];
  const int kk = blockIdx.x;            // 0..107
  const int o = kk / 12;
  const int chunk = kk - o * 12;
  const float* src = W1 + (o * 384 + chunk * 32) * 128;  // [c][n], n contiguous
  const int t = threadIdx.x;
#pragma unroll
  for (int i = 0; i < 16; ++i) {
    int idx = t + i * 256;              // idx = c*128+n
    int c = idx >> 7;
    int n = idx & 127;
    tile[n * 32 + c] = f2bf_rne(src[idx]);
  }
  __syncthreads();
  unsigned short* dst = W1b + kk * 4096;
#pragma unroll
  for (int i = 0; i < 16; ++i) {
    int idx = t + i * 256;
    dst[idx] = tile[idx];
  }
}

// ---- staging: load 8 ch of halo item JJ into DST (zero-fill if invalid) ----
#define SLOAD(DST, JJ, CHOFF)                                                \
  if ((smask >> (JJ)) & 1) {                                                 \
    *(float4*)&DST[0] = *(const float4*)(x + soff[JJ] + (CHOFF));            \
    *(float4*)&DST[4] = *(const float4*)(x + soff[JJ] + (CHOFF) + 4);        \
  } else {                                                                   \
    _Pragma("unroll") for (int e = 0; e < 8; ++e) DST[e] = 0.0f;             \
  }

// ---- staging: pack + write item JJ to LDS write-buffer WB ----
#define SWRITE(SRC, JJ, WB)                                                  \
  if ((JJ) < 2 || t < 208)                                                   \
    *(ushort8*)&Ah[(WB) + ((t + ((JJ) << 8)) << 3)] = pack8(SRC);

// ---- prefetch 6 B-frags (3 oy x 2 nf) for (OX, chunk CC) into BUF ----
#define PREFETCH_B(BUF, OX, CC)                                              \
  _Pragma("unroll") for (int oy = 0; oy < 3; ++oy) {                         \
    const unsigned short* bp =                                               \
        W1b + (((oy * 3 + (OX)) * 12 + (CC)) << 12) + boff;                  \
    BUF[oy * 2 + 0] = *(const bf16x8*)bp;                                    \
    BUF[oy * 2 + 1] = *(const bf16x8*)(bp + 512);                            \
  }

// ---- tap-shared MFMA block: halo row hl feeds output row mi = hl-oy ----
#define MFMA_BLOCK(RB, OX, BUF)                                              \
  __builtin_amdgcn_s_setprio(1);                                             \
  _Pragma("unroll") for (int hl = 0; hl < 10; ++hl) {                        \
    const bf16x8 af =                                                        \
        *(const bf16x8*)&Ah[(RB) + ((hl * 18 + (OX)) << 5) + aoffl];         \
    _Pragma("unroll") for (int oy = 0; oy < 3; ++oy) {                       \
      const int mi = hl - oy;                                                \
      if (mi >= 0 && mi < 8) {                                               \
        acc[mi][0] = __builtin_amdgcn_mfma_f32_16x16x32_bf16(                \
            af, BUF[oy * 2 + 0], acc[mi][0], 0, 0, 0);                       \
        acc[mi][1] = __builtin_amdgcn_mfma_f32_16x16x32_bf16(                \
            af, BUF[oy * 2 + 1], acc[mi][1], 0, 0, 0);                       \
      }                                                                      \
    }                                                                        \
  }                                                                          \
  __builtin_amdgcn_s_setprio(0);

__global__ __launch_bounds__(256, 3) void conv_fused_kernel(
    const float* __restrict__ x, const unsigned short* __restrict__ W1b,
    const float* __restrict__ b1, const float* __restrict__ W2,
    const float* __restrict__ b2, float* __restrict__ out) {
  __shared__ alignas(16) unsigned short Ah[2 * E];  // 23040 B
  __shared__ float hsum[128 * 4];                   // 2048 B

  const int t = threadIdx.x;
  const int w = t >> 6;        // wave 0..3 -> n block [32w, 32w+32)
  const int lane = t & 63;
  const int g = lane >> 4;     // quad (k-sub / pixel-col quarter)
  const int lr = lane & 15;

  const int img = blockIdx.x >> 5;       // 32 images
  const int tid = blockIdx.x & 31;       // 8x4 grid of 8x16 tiles
  const int ty0 = (tid >> 2) << 3;
  const int tx0 = (tid & 3) << 4;

  // ---- staging plan: 720 items (halo px 0..179 x sub 0..3), 8 ch each ----
  // item = t + 256*j, j=0..2 (j=2 active only t<208). LDS unit = item
  // (flat [px][32ch] layout -> consecutive lanes write consecutive 16B).
  int smask = 0;
  int soff[3];
#pragma unroll
  for (int j = 0; j < 3; ++j) {
    int item = t + (j << 8);
    int px = item >> 2, sub = item & 3;
    int hy = (px * 57) >> 10;            // px/18 for px<1024
    int hx = px - hy * 18;
    int iy = ty0 + hy - 1, ix = tx0 + hx - 1;
    int v = (item < 720) && ((unsigned)iy < 64u) && ((unsigned)ix < 64u);
    smask |= (v << j);
    int iyc = v ? iy : 0, ixc = v ? ix : 0;
    soff[j] = ((((img << 6) + iyc) << 6) + ixc) * 384 + sub * 8;
  }

  // B frag offset (elems): row n = w*32 + lr (+16 for nf=1), k-sub = g*8
  const int boff = ((w * 32 + lr) << 5) + (g << 3);
  // A frag lane part (elems): halo px col lr (+ox), ch quarter g
  const int aoffl = (lr << 5) + (g << 3);

  floatx4 acc[8][2] = {};  // px row = mi, px col = g*4+r, ch = w*32+nf*16+lr

  const float b1v0 = b1[w * 32 + lr];
  const float b1v1 = b1[w * 32 + 16 + lr];
  const float w2v0 = W2[w * 32 + lr];
  const float w2v1 = W2[w * 32 + 16 + lr];

  float sA[8], sB[8];
  bf16x8 bfU[6], bfV[6];

  // ---- prologue: stage chunk 0 into buf0; prefetch B for (c=0, ox=0) ----
  {
    SLOAD(sA, 0, 0)
    SLOAD(sB, 1, 0)
    SWRITE(sA, 0, 0)
    SLOAD(sA, 2, 0)
    SWRITE(sB, 1, 0)
    SWRITE(sA, 2, 0)
    PREFETCH_B(bfU, 0, 0)
  }
  __syncthreads();

  for (int c = 0; c < 12; c += 2) {
    const int cB = c + 1;
    const bool pfB = (c < 10);
    const int chA = (c + 1) << 5;
    const int chB = (c + 2) << 5;

    // ======== chunk A: read buf 0, write buf E ========
    PREFETCH_B(bfV, 1, c)
    SLOAD(sA, 0, chA)
    MFMA_BLOCK(0, 0, bfU)

    PREFETCH_B(bfU, 2, c)
    SLOAD(sB, 1, chA)
    SWRITE(sA, 0, E)
    MFMA_BLOCK(0, 1, bfV)

    PREFETCH_B(bfV, 0, cB)
    SLOAD(sA, 2, chA)
    SWRITE(sB, 1, E)
    MFMA_BLOCK(0, 2, bfU)

    SWRITE(sA, 2, E)
    BARRIER_NODRAIN()

    // ======== chunk B: read buf E, write buf 0 ========
    PREFETCH_B(bfU, 1, cB)
    if (pfB) { SLOAD(sA, 0, chB) }
    MFMA_BLOCK(E, 0, bfV)

    PREFETCH_B(bfV, 2, cB)
    if (pfB) { SLOAD(sB, 1, chB) SWRITE(sA, 0, 0) }
    MFMA_BLOCK(E, 1, bfU)

    {
      const int cn = (c + 2 < 12) ? c + 2 : 11;
      PREFETCH_B(bfU, 0, cn)
    }
    if (pfB) { SLOAD(sA, 2, chB) SWRITE(sB, 1, 0) }
    MFMA_BLOCK(E, 2, bfV)

    if (pfB) { SWRITE(sA, 2, 0) }
    BARRIER_NODRAIN()
  }

  // ---- epilogue: bias+relu, conv1x1 reduce over n, sigmoid ----
#pragma unroll
  for (int mi = 0; mi < 8; ++mi) {
#pragma unroll
    for (int r = 0; r < 4; ++r) {
      float h0 = fmaxf(acc[mi][0][r] + b1v0, 0.0f);
      float h1 = fmaxf(acc[mi][1][r] + b1v1, 0.0f);
      float v = h0 * w2v0 + h1 * w2v1;
      v += __shfl_xor(v, 1);
      v += __shfl_xor(v, 2);
      v += __shfl_xor(v, 4);
      v += __shfl_xor(v, 8);
      if (lr == 0) {
        int m = mi * 16 + g * 4 + r;  // pixel row = mi, pixel col = g*4+r
        hsum[m * 4 + w] = v;
      }
    }
  }
  __syncthreads();
  if (t < 128) {
    float4 p = *(const float4*)&hsum[t * 4];
    float s = p.x + p.y + p.z + p.w + b2[0];
    float sig = 1.0f / (1.0f + expf(-s));
    int prow = t >> 4, pcol = t & 15;
    out[((((img << 6) + ty0 + prow) << 6) + tx0 + pcol)] = sig;
  }
}

extern "C" void kernel_launch(void* const* d_in, const int* in_sizes, int n_in,
                              void* d_out, int out_size, void* d_ws, size_t ws_size,
                              hipStream_t stream) {
  const float* x  = (const float*)d_in[0];   // (32,64,64,384)
  const float* W1 = (const float*)d_in[1];   // (3,3,384,128)
  const float* b1 = (const float*)d_in[2];   // (128)
  const float* W2 = (const float*)d_in[3];   // (128)
  const float* b2 = (const float*)d_in[4];   // (1)
  float* out = (float*)d_out;                // (32,64,64,1)
  unsigned short* W1b = (unsigned short*)d_ws;  // 108*4096*2 = 884736 B

  prep_w1_kernel<<<108, 256, 0, stream>>>(W1, W1b);
  conv_fused_kernel<<<1024, 256, 0, stream>>>(x, W1b, b1, W2, b2, out);
}

// Round 6
// 333.176 us; speedup vs baseline: 1.0118x; 1.0118x over previous
//
#include <hip/hip_runtime.h>
#include <hip/hip_bf16.h>
#include <math.h>

// B=32, H=64, W=64, C_IN=384, C_HID=128
// conv3x3(pad1)+b1 -> relu -> conv1x1+b2 -> sigmoid, NHWC fp32.
// Implicit GEMM, halo-LDS (double-buffered), tap-sharing, BIG M:
//   per block: 16x16 output pixels (M=256), N=128, K=9*384. Grid 512 = 2/CU.
//   chunk loop (12 x 32ch): one barrier/chunk; halo 18x18 px x 32ch bf16.
// R6 = R3 geometry (2Mx4N) + register diet -> 2 blocks/CU:
//   * Cycle budget (m134: ds_read_b128 ~12cyc/CU): R2's N-split had all 16
//     waves/CU reading the whole halo = 10.4K LDS cyc/chunk vs 11.2K MFMA
//     -> co-critical, explains the 2x-floor plateau. M-split (R3) cuts af
//     reads 54->30/wave/chunk but R3's 72+64=136 regs dropped to 1 block/CU
//     (occupancy cliff) and masked the gain. R6 removes the confound.
//   * Register diet: (a) staging packs to bf16 at load, ONE item per
//     ox-phase (su0/su1/su2 ushort8, peak 12 VGPR vs 24 float),
//     (b) b1/W2 loads sunk to epilogue, (c) plain __syncthreads (R5's
//     no-drain barrier null -> reverted), no B ping-pong (R4 null).
//     Target <=64 arch + 64 acc = 128 -> __launch_bounds__(512,4).
//   * Keep: s_setprio around MFMA, per-ox B-frag hoist, flat [px][32ch]
//     halo, no swizzle (SQ_LDS_BANK_CONFLICT proven structural 4/read).

typedef __attribute__((ext_vector_type(8))) unsigned short ushort8;
typedef __attribute__((ext_vector_type(8))) __bf16 bf16x8;
typedef __attribute__((ext_vector_type(4))) float floatx4;

#define HPX 324            // 18*18 halo pixels
#define BUFE 10368         // HPX*32 elems per chunk buffer

static __device__ __forceinline__ unsigned short f2bf_rne(float f) {
  union { float f; unsigned int u; } x; x.f = f;
  unsigned int u = x.u;
  return (unsigned short)((u + 0x7fffu + ((u >> 16) & 1u)) >> 16);
}

static __device__ __forceinline__ ushort8 pack8(const float* v) {
  ushort8 r;
#pragma unroll
  for (int i = 0; i < 4; ++i) {
    __hip_bfloat162 p = __float22bfloat162_rn(make_float2(v[2 * i], v[2 * i + 1]));
    union { __hip_bfloat162 b; unsigned int u; } c;
    c.b = p;
    r[2 * i] = (unsigned short)(c.u & 0xffffu);
    r[2 * i + 1] = (unsigned short)(c.u >> 16);
  }
  return r;
}

// W1 (3,3,384,128 HWIO fp32) -> bf16 W1b[kk][n][c], kk=o*12+chunk, n=0..127, c=0..31.
__global__ void prep_w1_kernel(const float* __restrict__ W1,
                               unsigned short* __restrict__ W1b) {
  __shared__ unsigned short tile[32 * 128];
  const int kk = blockIdx.x;            // 0..107
  const int o = kk / 12;
  const int chunk = kk - o * 12;
  const float* src = W1 + (o * 384 + chunk * 32) * 128;  // [c][n], n contiguous
  const int t = threadIdx.x;
#pragma unroll
  for (int i = 0; i < 16; ++i) {
    int idx = t + i * 256;              // idx = c*128+n
    int c = idx >> 7;
    int n = idx & 127;
    tile[n * 32 + c] = f2bf_rne(src[idx]);
  }
  __syncthreads();
  unsigned short* dst = W1b + kk * 4096;
#pragma unroll
  for (int i = 0; i < 16; ++i) {
    int idx = t + i * 256;
    dst[idx] = tile[idx];
  }
}

// ---- staging: load 8 ch of halo item JJ, pack to bf16 ushort8 DST ----
#define SLOADP(DST, JJ, CHOFF)                                               \
  {                                                                          \
    float tf[8];                                                             \
    if ((smask >> (JJ)) & 1) {                                               \
      *(float4*)&tf[0] = *(const float4*)(x + soff[JJ] + (CHOFF));           \
      *(float4*)&tf[4] = *(const float4*)(x + soff[JJ] + (CHOFF) + 4);       \
    } else {                                                                 \
      _Pragma("unroll") for (int e = 0; e < 8; ++e) tf[e] = 0.0f;            \
    }                                                                        \
    DST = pack8(tf);                                                         \
  }

// ---- staging: write packed item JJ to LDS write-buffer WB ----
#define SWRITE8(SRC, JJ, WB)                                                 \
  if ((JJ) < 2 || t < 272)                                                   \
    *(ushort8*)&Ah[(WB) + ((t + ((JJ) << 9)) << 3)] = SRC;

__global__ __launch_bounds__(512, 4) void conv_fused_kernel(
    const float* __restrict__ x, const unsigned short* __restrict__ W1b,
    const float* __restrict__ b1, const float* __restrict__ W2,
    const float* __restrict__ b2, float* __restrict__ out) {
  __shared__ alignas(16) unsigned short Ah[2 * BUFE];  // 41472 B
  __shared__ float hsum[256 * 4];                      // 4096 B

  const int t = threadIdx.x;
  const int w = t >> 6;        // wave 0..7
  const int wm = w >> 2;       // M half: pixel rows [8*wm, 8*wm+8)
  const int wn = w & 3;        // N quarter: channels [32*wn, 32*wn+32)
  const int lane = t & 63;
  const int g = lane >> 4;     // quad (k-sub / pixel-col quarter)
  const int lr = lane & 15;

  const int img = blockIdx.x >> 4;       // 32 images
  const int tileId = blockIdx.x & 15;    // 4x4 grid of 16x16 tiles
  const int ty0 = (tileId >> 2) << 4;
  const int tx0 = (tileId & 3) << 4;

  // ---- staging plan: 1296 items (halo px 0..323 x sub 0..3), 8 ch each ----
  // item = t + 512*j, j=0..2 (j=2 active only t<272). LDS unit = item
  // (flat [px][32ch] layout -> consecutive lanes write consecutive 16B).
  int smask = 0;
  int soff[3];
#pragma unroll
  for (int j = 0; j < 3; ++j) {
    int item = t + (j << 9);
    int px = item >> 2, sub = item & 3;
    int hy = (px * 57) >> 10;            // px/18 for px<1024
    int hx = px - hy * 18;
    int iy = ty0 + hy - 1, ix = tx0 + hx - 1;
    int v = (item < 1296) && ((unsigned)iy < 64u) && ((unsigned)ix < 64u);
    smask |= (v << j);
    int iyc = v ? iy : 0, ixc = v ? ix : 0;
    soff[j] = ((((img << 6) + iyc) << 6) + ixc) * 384 + sub * 8;
  }

  // B frag offset (elems): row n = wn*32 + lr (+16 for nf=1), k-sub = g*8
  const int boff = ((wn * 32 + lr) << 5) + (g << 3);
  // A frag lane part (elems): halo px col lr (+ox), ch quarter g
  const int aoffl = (lr << 5) + (g << 3);

  floatx4 acc[8][2] = {};  // px row = wm*8+mi, px col = g*4+r, ch = wn*32+nf*16+lr

  ushort8 su0, su1, su2;

  // ---- prologue: stage chunk 0 into buf0 ----
  {
    SLOADP(su0, 0, 0)
    SLOADP(su1, 1, 0)
    SLOADP(su2, 2, 0)
    SWRITE8(su0, 0, 0)
    SWRITE8(su1, 1, 0)
    SWRITE8(su2, 2, 0)
  }
  __syncthreads();

  for (int c = 0; c < 12; ++c) {
    const int rb = (c & 1) * BUFE;        // read buffer (chunk c)
    const int wb = BUFE - rb;             // write buffer (chunk c+1)
    const int choff = (c + 1) << 5;
    const bool pf = (c < 11);

#pragma unroll
    for (int ox = 0; ox < 3; ++ox) {
      // ---- B frags for this ox (6 x 16B from L2-resident W1b) ----
      bf16x8 bf[3][2];
#pragma unroll
      for (int oy = 0; oy < 3; ++oy) {
        const unsigned short* bp =
            W1b + (((oy * 3 + ox) * 12 + c) << 12) + boff;
        bf[oy][0] = *(const bf16x8*)bp;
        bf[oy][1] = *(const bf16x8*)(bp + 512);
      }

      // ---- staging: one item per ox-phase (load+pack here, write next) ----
      if (pf) {
        if (ox == 0) {
          SLOADP(su0, 0, choff)
        } else if (ox == 1) {
          SWRITE8(su0, 0, wb)
          SLOADP(su1, 1, choff)
        } else {
          SWRITE8(su1, 1, wb)
          SLOADP(su2, 2, choff)
        }
      }

      // ---- tap-shared MFMAs over this wave's 10 halo rows ----
      // halo row hg = wm*8 + hl feeds output row mi = hl - oy (0..7).
      __builtin_amdgcn_s_setprio(1);
#pragma unroll
      for (int hl = 0; hl < 10; ++hl) {
        const int hg = wm * 8 + hl;      // wm uniform per wave
        const bf16x8 af =
            *(const bf16x8*)&Ah[rb + ((hg * 18 + ox) << 5) + aoffl];
#pragma unroll
        for (int oy = 0; oy < 3; ++oy) {
          const int mi = hl - oy;
          if (mi >= 0 && mi < 8) {
            acc[mi][0] = __builtin_amdgcn_mfma_f32_16x16x32_bf16(
                af, bf[oy][0], acc[mi][0], 0, 0, 0);
            acc[mi][1] = __builtin_amdgcn_mfma_f32_16x16x32_bf16(
                af, bf[oy][1], acc[mi][1], 0, 0, 0);
          }
        }
      }
      __builtin_amdgcn_s_setprio(0);
    }
    if (pf) { SWRITE8(su2, 2, wb) }
    __syncthreads();
  }

  // ---- epilogue: bias+relu, conv1x1 reduce over n, sigmoid ----
  const float b1v0 = b1[wn * 32 + lr];
  const float b1v1 = b1[wn * 32 + 16 + lr];
  const float w2v0 = W2[wn * 32 + lr];
  const float w2v1 = W2[wn * 32 + 16 + lr];
#pragma unroll
  for (int mi = 0; mi < 8; ++mi) {
#pragma unroll
    for (int r = 0; r < 4; ++r) {
      float h0 = fmaxf(acc[mi][0][r] + b1v0, 0.0f);
      float h1 = fmaxf(acc[mi][1][r] + b1v1, 0.0f);
      float v = h0 * w2v0 + h1 * w2v1;
      v += __shfl_xor(v, 1);
      v += __shfl_xor(v, 2);
      v += __shfl_xor(v, 4);
      v += __shfl_xor(v, 8);
      if (lr == 0) {
        int m = (wm * 8 + mi) * 16 + g * 4 + r;  // pixel row, pixel col
        hsum[m * 4 + wn] = v;
      }
    }
  }
  __syncthreads();
  if (t < 256) {
    float4 p = *(const float4*)&hsum[t * 4];
    float s = p.x + p.y + p.z + p.w + b2[0];
    float sig = 1.0f / (1.0f + expf(-s));
    int prow = t >> 4, pcol = t & 15;
    out[((((img << 6) + ty0 + prow) << 6) + tx0 + pcol)] = sig;
  }
}

extern "C" void kernel_launch(void* const* d_in, const int* in_sizes, int n_in,
                              void* d_out, int out_size, void* d_ws, size_t ws_size,
                              hipStream_t stream) {
  const float* x  = (const float*)d_in[0];   // (32,64,64,384)
  const float* W1 = (const float*)d_in[1];   // (3,3,384,128)
  const float* b1 = (const float*)d_in[2];   // (128)
  const float* W2 = (const float*)d_in[3];   // (128)
  const float* b2 = (const float*)d_in[4];   // (1)
  float* out = (float*)d_out;                // (32,64,64,1)
  unsigned short* W1b = (unsigned short*)d_ws;  // 108*4096*2 = 884736 B

  prep_w1_kernel<<<108, 256, 0, stream>>>(W1, W1b);
  conv_fused_kernel<<<512, 512, 0, stream>>>(x, W1b, b1, W2, b2, out);
}